// Round 3
// baseline (1829.387 us; speedup 1.0000x reference)
//
#include <hip/hip_runtime.h>
#include <cstdint>

#define TT  3
#define FIN 4
#define HID 128

typedef unsigned int   u32;
typedef unsigned short u16;
typedef unsigned long long u64;
typedef float f32x4 __attribute__((ext_vector_type(4)));
typedef __bf16 bf16x8 __attribute__((ext_vector_type(8)));

static __device__ __forceinline__ f32x4 mfma_bf16(bf16x8 a, bf16x8 b, f32x4 c) {
  return __builtin_amdgcn_mfma_f32_16x16x32_bf16(a, b, c, 0, 0, 0);
}
static __device__ __forceinline__ float sigf(float v) { return 1.f / (1.f + expf(-v)); }
static __device__ __forceinline__ float bf_lo(u32 u) { return __uint_as_float(u << 16); }
static __device__ __forceinline__ float bf_hi(u32 u) { return __uint_as_float(u & 0xffff0000u); }
static __device__ __forceinline__ u16 bfbits(float f) {
  return __builtin_bit_cast(unsigned short, (__bf16)f);
}

// fused BN-stats tail: block reduce -> replicated atomics -> ticket last-block affine
static __device__ __forceinline__ void stats_tail(
    float (*red)[4], int* lastf,
    float s1a, float s2a, float s1b, float s2b,
    float* statsbuf, int* ticket,
    const float* gamma, const float* beta, float* aout, float* bout, int N_) {
  int l = threadIdx.x & 63;
  red[threadIdx.x][0] = s1a; red[threadIdx.x][1] = s2a;
  red[threadIdx.x][2] = s1b; red[threadIdx.x][3] = s2b;
  __syncthreads();
  if ((threadIdx.x >> 6) == 0) {
    float a0 = 0, a1 = 0, a2 = 0, a3 = 0;
    #pragma unroll
    for (int h2 = 0; h2 < 4; ++h2) {
      a0 += red[h2*64 + l][0]; a1 += red[h2*64 + l][1];
      a2 += red[h2*64 + l][2]; a3 += red[h2*64 + l][3];
    }
    float* sb = statsbuf + (size_t)(blockIdx.x & 15) * 256;
    atomicAdd(&sb[2*l], a0);       atomicAdd(&sb[HID + 2*l], a1);
    atomicAdd(&sb[2*l + 1], a2);   atomicAdd(&sb[HID + 2*l + 1], a3);
  }
  __syncthreads();
  if (threadIdx.x == 0) {
    __threadfence();
    int tk = __hip_atomic_fetch_add(ticket, 1, __ATOMIC_ACQ_REL, __HIP_MEMORY_SCOPE_AGENT);
    *lastf = (tk == (int)gridDim.x - 1) ? 1 : 0;
  }
  __syncthreads();
  if (*lastf) {
    if (threadIdx.x < HID) {
      int c = threadIdx.x;
      float s1 = 0.f, s2 = 0.f;
      #pragma unroll
      for (int k = 0; k < 16; ++k) {
        s1 += __hip_atomic_load(&statsbuf[k*256 + c],       __ATOMIC_RELAXED, __HIP_MEMORY_SCOPE_AGENT);
        s2 += __hip_atomic_load(&statsbuf[k*256 + HID + c], __ATOMIC_RELAXED, __HIP_MEMORY_SCOPE_AGENT);
      }
      float invn = 1.f / (float)N_;
      float mu = s1 * invn;
      float var = fmaxf(s2 * invn - mu * mu, 0.f);
      float a = gamma[c] * rsqrtf(var + 1e-5f);
      aout[c] = a;
      bout[c] = beta[c] - mu * a;
    }
    __syncthreads();
    for (int i = threadIdx.x; i < 4096; i += 256) statsbuf[i] = 0.f;
    if (threadIdx.x == 0) *ticket = 0;
  }
}

// ---------------- graph preprocessing ----------------

__global__ void k_init(u64* pk, float* statsbuf, int* ticket, int n) {
  int i = blockIdx.x * 256 + threadIdx.x;
  if (i < n) pk[i] = 0ull;
  if (blockIdx.x == 0) {
    for (int k = 0; k < 16; ++k) statsbuf[k * 256 + threadIdx.x] = 0.f;
    if (threadIdx.x == 0) *ticket = 0;
  }
}

// one u64 atomic per edge: hi 22 bits = count, low 42 bits = Q10.32 weight sum.
__global__ void k_deg(const int* __restrict__ dstv, const float* __restrict__ ew,
                      u64* pk, int* __restrict__ epos, int E_) {
  int e = blockIdx.x * 256 + threadIdx.x;
  if (e < E_) {
    int d = dstv[e];
    u64 inc = (1ull << 42) | (u64)(ew[e] * 4294967296.0f);
    u64 old = atomicAdd(&pk[d], inc);
    epos[e] = (int)(old >> 42);
  }
}

__global__ __launch_bounds__(256) void k_scanA(const u64* __restrict__ pk, int* rowptr,
    int* partial, float* dinv, float* selfn, int n) {
  __shared__ int wsum[4];
  int tid = threadIdx.x, lane = tid & 63, wv = tid >> 6;
  int i = blockIdx.x * 256 + tid;
  int v = 0;
  if (i < n) {
    u64 p = pk[i];
    v = (int)(p >> 42);
    float degw = (float)((double)(p & ((1ull << 42) - 1)) * (1.0 / 4294967296.0) + 1.0);
    float r = rsqrtf(degw);
    dinv[i] = r; selfn[i] = r * r;
  }
  int inc = v;
  #pragma unroll
  for (int off = 1; off < 64; off <<= 1) {
    int t2 = __shfl_up(inc, off);
    if (lane >= off) inc += t2;
  }
  if (lane == 63) wsum[wv] = inc;
  __syncthreads();
  if (tid == 0) {
    int s = 0;
    #pragma unroll
    for (int j = 0; j < 4; ++j) { int t3 = wsum[j]; wsum[j] = s; s += t3; }
    partial[blockIdx.x] = s;
  }
  __syncthreads();
  int excl = wsum[wv] + inc - v;
  if (i <= n) rowptr[i] = excl;
}

__global__ __launch_bounds__(256) void k_scanB(int* partial, int nb) {
  __shared__ int wsum[4];
  int tid = threadIdx.x, lane = tid & 63, wv = tid >> 6;
  int v = (tid < nb) ? partial[tid] : 0;
  int inc = v;
  #pragma unroll
  for (int off = 1; off < 64; off <<= 1) {
    int t2 = __shfl_up(inc, off);
    if (lane >= off) inc += t2;
  }
  if (lane == 63) wsum[wv] = inc;
  __syncthreads();
  if (tid == 0) {
    int s = 0;
    #pragma unroll
    for (int j = 0; j < 4; ++j) { int t3 = wsum[j]; wsum[j] = s; s += t3; }
  }
  __syncthreads();
  int excl = wsum[wv] + inc - v;
  if (tid < nb) partial[tid] = excl;
}

__global__ void k_scanC(int* rowptr, const int* __restrict__ partial, int n) {
  int i = blockIdx.x * 256 + threadIdx.x;
  if (i <= n) rowptr[i] += partial[blockIdx.x];
}

__global__ void k_fillcsr(const int* __restrict__ srcv, const int* __restrict__ dstv,
                          const float* __restrict__ ew, const float* __restrict__ dinv,
                          const int* __restrict__ rowptr, const int* __restrict__ epos,
                          int2* __restrict__ csr, int E_) {
  int e = blockIdx.x * 256 + threadIdx.x;
  if (e < E_) {
    int d = dstv[e], s = srcv[e];
    int idx = rowptr[d] + epos[e];
    csr[idx] = make_int2(s, __float_as_int(dinv[s] * ew[e] * dinv[d]));
  }
}

// ---------------- layer-0: aggregate X (12 feats) ----------------

__global__ __launch_bounds__(256) void k_aggX(const float* __restrict__ X,
    const int* __restrict__ rowptr, const int2* __restrict__ csr,
    const float* __restrict__ selfn, float* __restrict__ XA, int N_) {
  int wv = threadIdx.x >> 6, l = threadIdx.x & 63;
  int wid = blockIdx.x * 4 + wv, nw = gridDim.x * 4;
  for (int n = wid; n < N_; n += nw) {
    float acc[12];
    #pragma unroll
    for (int i = 0; i < 12; ++i) acc[i] = 0.f;
    int e0 = rowptr[n], e1 = rowptr[n + 1];
    for (int e = e0 + l; e < e1; e += 64) {
      int2 v2 = csr[e];
      int s = v2.x; float wn = __int_as_float(v2.y);
      #pragma unroll
      for (int t = 0; t < TT; ++t) {
        float4 v = *(const float4*)(X + ((size_t)t * N_ + s) * FIN);
        acc[t*4+0] += wn * v.x; acc[t*4+1] += wn * v.y;
        acc[t*4+2] += wn * v.z; acc[t*4+3] += wn * v.w;
      }
    }
    #pragma unroll
    for (int i = 0; i < 12; ++i)
      for (int off = 32; off; off >>= 1) acc[i] += __shfl_down(acc[i], off);
    if (l == 0) {
      float sn = selfn[n];
      #pragma unroll
      for (int t = 0; t < TT; ++t) {
        float4 v = *(const float4*)(X + ((size_t)t * N_ + n) * FIN);
        XA[(size_t)n*12 + t*4+0] = acc[t*4+0] + sn * v.x;
        XA[(size_t)n*12 + t*4+1] = acc[t*4+1] + sn * v.y;
        XA[(size_t)n*12 + t*4+2] = acc[t*4+2] + sn * v.z;
        XA[(size_t)n*12 + t*4+3] = acc[t*4+3] + sn * v.w;
      }
    }
  }
}

// layer-0 transform + relu + fused BN stats
__global__ __launch_bounds__(256) void k_l0s(const float* __restrict__ XA,
    const float* __restrict__ w1, const float* __restrict__ bc0, u32* __restrict__ out32,
    float* statsbuf, int* ticket, const float* __restrict__ gamma,
    const float* __restrict__ beta, float* aout, float* bout, int t, int N_) {
  __shared__ float red[256][4];
  __shared__ int lastf;
  int l = threadIdx.x & 63, half = threadIdx.x >> 6;
  int cp = 2 * l;
  float w00 = w1[cp],         w01 = w1[cp+1];
  float w10 = w1[HID+cp],     w11 = w1[HID+cp+1];
  float w20 = w1[2*HID+cp],   w21 = w1[2*HID+cp+1];
  float w30 = w1[3*HID+cp],   w31 = w1[3*HID+cp+1];
  float b0 = bc0[cp], b1 = bc0[cp+1];
  float s1a = 0, s2a = 0, s1b = 0, s2b = 0;
  for (int n = blockIdx.x * 4 + half; n < N_; n += gridDim.x * 4) {
    float4 x = *(const float4*)(XA + (size_t)n * 12 + t * 4);
    float v0 = fmaxf(b0 + x.x*w00 + x.y*w10 + x.z*w20 + x.w*w30, 0.f);
    float v1 = fmaxf(b1 + x.x*w01 + x.y*w11 + x.z*w21 + x.w*w31, 0.f);
    s1a += v0; s2a += v0*v0; s1b += v1; s2b += v1*v1;
    out32[(size_t)n * 64 + l] = (u32)bfbits(v0) | ((u32)bfbits(v1) << 16);
  }
  stats_tail(red, &lastf, s1a, s2a, s1b, s2b, statsbuf, ticket, gamma, beta, aout, bout, N_);
}

// ---------------- weight swizzles ----------------

__global__ void k_swzall(const float* __restrict__ wc, const float* __restrict__ wih,
                         const float* __restrict__ whh,
                         bf16x8* __restrict__ wcsw, bf16x8* __restrict__ wstk) {
  int id = blockIdx.x * 256 + threadIdx.x;
  if (id < 6144) {
    int i = id >> 11, lid = id & 2047;
    int l = lid & 63, frag = lid >> 6;
    int cb = frag & 7, kb = frag >> 3;
    int col = cb * 16 + (l & 15);
    int k0 = kb * 32 + (l >> 4) * 8;
    const float* W = wc + (size_t)i * HID * HID;
    bf16x8 v;
    #pragma unroll
    for (int j = 0; j < 8; ++j) v[j] = (__bf16)W[(size_t)(k0 + j) * HID + col];
    wcsw[i * 2048 + lid] = v;
  } else if (id < 6144 + 32768) {
    int id2 = id - 6144;
    int layer = id2 >> 14, lid = id2 & 16383;
    int l = lid & 63, frag = lid >> 6;
    int cb = frag & 31, kb = frag >> 5;
    int col = cb * 16 + (l & 15);
    int k0 = kb * 32 + (l >> 4) * 8;
    const float* wi = wih + (size_t)layer * 512 * HID;
    const float* wh = whh + (size_t)layer * 512 * HID;
    bf16x8 v;
    #pragma unroll
    for (int j = 0; j < 8; ++j) {
      int k = k0 + j;
      float val = (k < HID) ? wi[(size_t)col * HID + k] : wh[(size_t)col * HID + (k - HID)];
      v[j] = (__bf16)val;
    }
    wstk[layer * 16384 + lid] = v;
  }
}

// collapsed head: Wc[k] = sum_j lin1_w[k][j]*lin2_w[j]; b = lin1_b@lin2_w + lin2_b
__global__ void k_headprep(const float* __restrict__ l1w, const float* __restrict__ l1b,
                           const float* __restrict__ l2w, const float* __restrict__ l2b,
                           float* __restrict__ hw) {
  int k = threadIdx.x;
  if (k < HID + TT) {
    float s = 0.f;
    for (int j = 0; j < HID; ++j) s += l1w[(size_t)k * HID + j] * l2w[j];
    hw[k] = s;
  } else if (k == HID + TT) {
    float s = l2b[0];
    for (int j = 0; j < HID; ++j) s += l1b[j] * l2w[j];
    hw[HID + TT] = s;
  }
}

// ---------------- MFMA transform: Y = affine(bf16 X) @ W, bf16 out ----------------

__global__ __launch_bounds__(256) void k_trans(const u16* __restrict__ Xin,
    const float* __restrict__ fa, const float* __restrict__ fb,
    const bf16x8* __restrict__ wsw, u16* __restrict__ Y, int N_) {
  int w = threadIdx.x >> 6, l = threadIdx.x & 63;
  int lr = l & 15, lk = l >> 4;
  int rbase = blockIdx.x * 64 + w * 16;
  int arow = rbase + lr;
  bool av = arow < N_;
  f32x4 acc[8];
  #pragma unroll
  for (int cb = 0; cb < 8; ++cb) acc[cb] = (f32x4){0.f, 0.f, 0.f, 0.f};
  #pragma unroll
  for (int kb = 0; kb < 4; ++kb) {
    int ko = kb * 32 + lk * 8;
    bf16x8 af;
    if (av) {
      uint4 u = *(const uint4*)(Xin + (size_t)arow * HID + ko);
      float4 a0 = *(const float4*)(fa + ko), a1 = *(const float4*)(fa + ko + 4);
      float4 b0 = *(const float4*)(fb + ko), b1 = *(const float4*)(fb + ko + 4);
      af[0] = (__bf16)(bf_lo(u.x) * a0.x + b0.x);
      af[1] = (__bf16)(bf_hi(u.x) * a0.y + b0.y);
      af[2] = (__bf16)(bf_lo(u.y) * a0.z + b0.z);
      af[3] = (__bf16)(bf_hi(u.y) * a0.w + b0.w);
      af[4] = (__bf16)(bf_lo(u.z) * a1.x + b1.x);
      af[5] = (__bf16)(bf_hi(u.z) * a1.y + b1.y);
      af[6] = (__bf16)(bf_lo(u.w) * a1.z + b1.z);
      af[7] = (__bf16)(bf_hi(u.w) * a1.w + b1.w);
    } else {
      #pragma unroll
      for (int j = 0; j < 8; ++j) af[j] = (__bf16)0.f;
    }
    #pragma unroll
    for (int cb = 0; cb < 8; ++cb) {
      bf16x8 bf = wsw[(kb * 8 + cb) * 64 + l];
      acc[cb] = mfma_bf16(af, bf, acc[cb]);
    }
  }
  #pragma unroll
  for (int cb = 0; cb < 8; ++cb)
    #pragma unroll
    for (int i2 = 0; i2 < 4; ++i2) {
      int orow = rbase + lk * 4 + i2;
      if (orow < N_) Y[(size_t)orow * HID + cb * 16 + lr] = bfbits(acc[cb][i2]);
    }
}

// ---------------- 128-wide aggregation + bias + relu + fused BN stats ----------------

__global__ __launch_bounds__(256) void k_aggs(const u32* __restrict__ H32,
    const int* __restrict__ rowptr, const int2* __restrict__ csr,
    const float* __restrict__ selfn, const float* __restrict__ bias,
    u32* __restrict__ out32, float* statsbuf, int* ticket,
    const float* __restrict__ gamma, const float* __restrict__ beta,
    float* aout, float* bout, int N_) {
  __shared__ float red[256][4];
  __shared__ int lastf;
  int wv = threadIdx.x >> 6, l = threadIdx.x & 63;
  int wid = blockIdx.x * 4 + wv, nw = gridDim.x * 4;
  float b0 = bias[2 * l], b1 = bias[2 * l + 1];
  float s1a = 0, s2a = 0, s1b = 0, s2b = 0;
  for (int n = wid; n < N_; n += nw) {
    u32 u = H32[(size_t)n * 64 + l];
    float sn = selfn[n];
    float a0 = sn * bf_lo(u);
    float a1 = sn * bf_hi(u);
    int e0 = rowptr[n], e1 = rowptr[n + 1];
    int e = e0;
    for (; e + 7 < e1; e += 8) {
      int2 c0 = csr[e],   c1 = csr[e+1], c2 = csr[e+2], c3 = csr[e+3];
      int2 c4 = csr[e+4], c5 = csr[e+5], c6 = csr[e+6], c7 = csr[e+7];
      u32 x0 = H32[(size_t)c0.x * 64 + l];
      u32 x1 = H32[(size_t)c1.x * 64 + l];
      u32 x2 = H32[(size_t)c2.x * 64 + l];
      u32 x3 = H32[(size_t)c3.x * 64 + l];
      u32 x4 = H32[(size_t)c4.x * 64 + l];
      u32 x5 = H32[(size_t)c5.x * 64 + l];
      u32 x6 = H32[(size_t)c6.x * 64 + l];
      u32 x7 = H32[(size_t)c7.x * 64 + l];
      a0 += __int_as_float(c0.y) * bf_lo(x0) + __int_as_float(c1.y) * bf_lo(x1)
          + __int_as_float(c2.y) * bf_lo(x2) + __int_as_float(c3.y) * bf_lo(x3)
          + __int_as_float(c4.y) * bf_lo(x4) + __int_as_float(c5.y) * bf_lo(x5)
          + __int_as_float(c6.y) * bf_lo(x6) + __int_as_float(c7.y) * bf_lo(x7);
      a1 += __int_as_float(c0.y) * bf_hi(x0) + __int_as_float(c1.y) * bf_hi(x1)
          + __int_as_float(c2.y) * bf_hi(x2) + __int_as_float(c3.y) * bf_hi(x3)
          + __int_as_float(c4.y) * bf_hi(x4) + __int_as_float(c5.y) * bf_hi(x5)
          + __int_as_float(c6.y) * bf_hi(x6) + __int_as_float(c7.y) * bf_hi(x7);
    }
    for (; e < e1; ++e) {
      int2 c0 = csr[e];
      u32 x0 = H32[(size_t)c0.x * 64 + l];
      float w0 = __int_as_float(c0.y);
      a0 += w0 * bf_lo(x0);
      a1 += w0 * bf_hi(x0);
    }
    float v0 = fmaxf(a0 + b0, 0.f), v1 = fmaxf(a1 + b1, 0.f);
    s1a += v0; s2a += v0*v0; s1b += v1; s2b += v1*v1;
    out32[(size_t)n * 64 + l] = (u32)bfbits(v0) | ((u32)bfbits(v1) << 16);
  }
  stats_tail(red, &lastf, s1a, s2a, s1b, s2b, statsbuf, ticket, gamma, beta, aout, bout, N_);
}

// ---------------- fused double-layer LSTM step ----------------

__global__ __launch_bounds__(256) void k_lstm2(
    const u16* __restrict__ xb, const float* __restrict__ aff,
    u16* __restrict__ h1g, float* __restrict__ c1g,
    u16* __restrict__ h2g, float* __restrict__ c2g,
    const bf16x8* __restrict__ w1sw, const bf16x8* __restrict__ w2sw,
    const float* __restrict__ b1, const float* __restrict__ b2,
    int first, int N_) {
  __shared__ __bf16 gl[32][512];     // 32 KiB gates
  __shared__ __bf16 h1l[32][136];    // padded: conflict-light b128 reads
  int w = threadIdx.x >> 6, l = threadIdx.x & 63;
  int lr = l & 15, lk = l >> 4;
  int r0 = blockIdx.x * 32;
  f32x4 acc[2][8];

  // ---- layer 1 GEMM: gates = affine(x) @ Wih1  (+ h1prev @ Whh1) ----
  #pragma unroll
  for (int rb = 0; rb < 2; ++rb)
    #pragma unroll
    for (int cb = 0; cb < 8; ++cb) acc[rb][cb] = (f32x4){0.f, 0.f, 0.f, 0.f};
  #pragma unroll
  for (int kb = 0; kb < 4; ++kb) {
    int ko = kb * 32 + lk * 8;
    bf16x8 af[2];
    #pragma unroll
    for (int rb = 0; rb < 2; ++rb) {
      int row = r0 + rb * 16 + lr;
      if (row < N_) {
        uint4 u = *(const uint4*)(xb + (size_t)row * HID + ko);
        float4 a0 = *(const float4*)(aff + ko),       a1 = *(const float4*)(aff + ko + 4);
        float4 b0 = *(const float4*)(aff + HID + ko), b1v = *(const float4*)(aff + HID + ko + 4);
        af[rb][0] = (__bf16)(bf_lo(u.x) * a0.x + b0.x);
        af[rb][1] = (__bf16)(bf_hi(u.x) * a0.y + b0.y);
        af[rb][2] = (__bf16)(bf_lo(u.y) * a0.z + b0.z);
        af[rb][3] = (__bf16)(bf_hi(u.y) * a0.w + b0.w);
        af[rb][4] = (__bf16)(bf_lo(u.z) * a1.x + b1v.x);
        af[rb][5] = (__bf16)(bf_hi(u.z) * a1.y + b1v.y);
        af[rb][6] = (__bf16)(bf_lo(u.w) * a1.z + b1v.z);
        af[rb][7] = (__bf16)(bf_hi(u.w) * a1.w + b1v.w);
      } else {
        #pragma unroll
        for (int j = 0; j < 8; ++j) af[rb][j] = (__bf16)0.f;
      }
    }
    #pragma unroll
    for (int cb = 0; cb < 8; ++cb) {
      bf16x8 bf = w1sw[(kb * 32 + w * 8 + cb) * 64 + l];
      acc[0][cb] = mfma_bf16(af[0], bf, acc[0][cb]);
      acc[1][cb] = mfma_bf16(af[1], bf, acc[1][cb]);
    }
  }
  if (!first) {
    #pragma unroll
    for (int kb = 0; kb < 4; ++kb) {
      int ko = kb * 32 + lk * 8;
      bf16x8 af[2];
      #pragma unroll
      for (int rb = 0; rb < 2; ++rb) {
        int row = r0 + rb * 16 + lr;
        if (row < N_) {
          af[rb] = __builtin_bit_cast(bf16x8, *(const uint4*)(h1g + (size_t)row * HID + ko));
        } else {
          #pragma unroll
          for (int j = 0; j < 8; ++j) af[rb][j] = (__bf16)0.f;
        }
      }
      #pragma unroll
      for (int cb = 0; cb < 8; ++cb) {
        bf16x8 bf = w1sw[((kb + 4) * 32 + w * 8 + cb) * 64 + l];
        acc[0][cb] = mfma_bf16(af[0], bf, acc[0][cb]);
        acc[1][cb] = mfma_bf16(af[1], bf, acc[1][cb]);
      }
    }
  }
  #pragma unroll
  for (int rb = 0; rb < 2; ++rb)
    #pragma unroll
    for (int cb = 0; cb < 8; ++cb)
      #pragma unroll
      for (int i2 = 0; i2 < 4; ++i2)
        gl[rb * 16 + lk * 4 + i2][w * 128 + cb * 16 + lr] = (__bf16)acc[rb][cb][i2];
  __syncthreads();

  // ---- layer 1 cell ----
  for (int it = threadIdx.x; it < 2048; it += 256) {
    int nl = it >> 6, p = it & 63, j = 2 * p;
    int n = r0 + nl;
    if (n >= N_) { *(u32*)&h1l[nl][j] = 0u; continue; }
    u32 gi = *(const u32*)&gl[nl][j];
    u32 gf = *(const u32*)&gl[nl][128 + j];
    u32 gg = *(const u32*)&gl[nl][256 + j];
    u32 go = *(const u32*)&gl[nl][384 + j];
    float2 bi = *(const float2*)&b1[j];
    float2 bff = *(const float2*)&b1[128 + j];
    float2 bg = *(const float2*)&b1[256 + j];
    float2 bo = *(const float2*)&b1[384 + j];
    float cp0 = 0.f, cp1 = 0.f;
    if (!first) { float2 c = *(const float2*)(c1g + (size_t)n * HID + j); cp0 = c.x; cp1 = c.y; }
    float cn0 = sigf(bf_lo(gf) + bff.x) * cp0 + sigf(bf_lo(gi) + bi.x) * tanhf(bf_lo(gg) + bg.x);
    float cn1 = sigf(bf_hi(gf) + bff.y) * cp1 + sigf(bf_hi(gi) + bi.y) * tanhf(bf_hi(gg) + bg.y);
    float hn0 = sigf(bf_lo(go) + bo.x) * tanhf(cn0);
    float hn1 = sigf(bf_hi(go) + bo.y) * tanhf(cn1);
    *(float2*)(c1g + (size_t)n * HID + j) = make_float2(cn0, cn1);
    u32 hp = (u32)bfbits(hn0) | ((u32)bfbits(hn1) << 16);
    *(u32*)(h1g + (size_t)n * HID + j) = hp;
    *(u32*)&h1l[nl][j] = hp;
  }
  __syncthreads();

  // ---- layer 2 GEMM: gates = h1 @ Wih2 (+ h2prev @ Whh2) ----
  #pragma unroll
  for (int rb = 0; rb < 2; ++rb)
    #pragma unroll
    for (int cb = 0; cb < 8; ++cb) acc[rb][cb] = (f32x4){0.f, 0.f, 0.f, 0.f};
  #pragma unroll
  for (int kb = 0; kb < 4; ++kb) {
    int ko = kb * 32 + lk * 8;
    bf16x8 af[2];
    #pragma unroll
    for (int rb = 0; rb < 2; ++rb)
      af[rb] = *(const bf16x8*)&h1l[rb * 16 + lr][ko];
    #pragma unroll
    for (int cb = 0; cb < 8; ++cb) {
      bf16x8 bf = w2sw[(kb * 32 + w * 8 + cb) * 64 + l];
      acc[0][cb] = mfma_bf16(af[0], bf, acc[0][cb]);
      acc[1][cb] = mfma_bf16(af[1], bf, acc[1][cb]);
    }
  }
  if (!first) {
    #pragma unroll
    for (int kb = 0; kb < 4; ++kb) {
      int ko = kb * 32 + lk * 8;
      bf16x8 af[2];
      #pragma unroll
      for (int rb = 0; rb < 2; ++rb) {
        int row = r0 + rb * 16 + lr;
        if (row < N_) {
          af[rb] = __builtin_bit_cast(bf16x8, *(const uint4*)(h2g + (size_t)row * HID + ko));
        } else {
          #pragma unroll
          for (int j = 0; j < 8; ++j) af[rb][j] = (__bf16)0.f;
        }
      }
      #pragma unroll
      for (int cb = 0; cb < 8; ++cb) {
        bf16x8 bf = w2sw[((kb + 4) * 32 + w * 8 + cb) * 64 + l];
        acc[0][cb] = mfma_bf16(af[0], bf, acc[0][cb]);
        acc[1][cb] = mfma_bf16(af[1], bf, acc[1][cb]);
      }
    }
  }
  #pragma unroll
  for (int rb = 0; rb < 2; ++rb)
    #pragma unroll
    for (int cb = 0; cb < 8; ++cb)
      #pragma unroll
      for (int i2 = 0; i2 < 4; ++i2)
        gl[rb * 16 + lk * 4 + i2][w * 128 + cb * 16 + lr] = (__bf16)acc[rb][cb][i2];
  __syncthreads();

  // ---- layer 2 cell ----
  for (int it = threadIdx.x; it < 2048; it += 256) {
    int nl = it >> 6, p = it & 63, j = 2 * p;
    int n = r0 + nl;
    if (n >= N_) continue;
    u32 gi = *(const u32*)&gl[nl][j];
    u32 gf = *(const u32*)&gl[nl][128 + j];
    u32 gg = *(const u32*)&gl[nl][256 + j];
    u32 go = *(const u32*)&gl[nl][384 + j];
    float2 bi = *(const float2*)&b2[j];
    float2 bff = *(const float2*)&b2[128 + j];
    float2 bg = *(const float2*)&b2[256 + j];
    float2 bo = *(const float2*)&b2[384 + j];
    float cp0 = 0.f, cp1 = 0.f;
    if (!first) { float2 c = *(const float2*)(c2g + (size_t)n * HID + j); cp0 = c.x; cp1 = c.y; }
    float cn0 = sigf(bf_lo(gf) + bff.x) * cp0 + sigf(bf_lo(gi) + bi.x) * tanhf(bf_lo(gg) + bg.x);
    float cn1 = sigf(bf_hi(gf) + bff.y) * cp1 + sigf(bf_hi(gi) + bi.y) * tanhf(bf_hi(gg) + bg.y);
    float hn0 = sigf(bf_lo(go) + bo.x) * tanhf(cn0);
    float hn1 = sigf(bf_hi(go) + bo.y) * tanhf(cn1);
    *(float2*)(c2g + (size_t)n * HID + j) = make_float2(cn0, cn1);
    *(u32*)(h2g + (size_t)n * HID + j) = (u32)bfbits(hn0) | ((u32)bfbits(hn1) << 16);
  }
}

// ---------------- final head: out[n] = relu(h2[n]) . Wc + S . Ws + b ----------------

__global__ __launch_bounds__(256) void k_final2(const u32* __restrict__ H2,
    const float* __restrict__ Xin, const float* __restrict__ hw,
    float* __restrict__ outp, int N_) {
  int wv = threadIdx.x >> 6, l = threadIdx.x & 63;
  int wid = blockIdx.x * 4 + wv, nw = gridDim.x * 4;
  float wc0 = hw[2 * l], wc1 = hw[2 * l + 1];
  float ws0 = hw[HID], ws1 = hw[HID + 1], ws2 = hw[HID + 2], bb = hw[HID + 3];
  for (int n = wid; n < N_; n += nw) {
    u32 u = H2[(size_t)n * 64 + l];
    float p = fmaxf(bf_lo(u), 0.f) * wc0 + fmaxf(bf_hi(u), 0.f) * wc1;
    #pragma unroll
    for (int off = 32; off; off >>= 1) p += __shfl_down(p, off);
    if (l == 0) {
      p += Xin[(size_t)n * FIN] * ws0
         + Xin[((size_t)N_ + n) * FIN] * ws1
         + Xin[((size_t)2 * N_ + n) * FIN] * ws2;
      outp[n] = p + bb;
    }
  }
}

// ---------------- host ----------------

extern "C" void kernel_launch(void* const* d_in, const int* in_sizes, int n_in,
                              void* d_out, int out_size, void* d_ws, size_t ws_size,
                              hipStream_t stream) {
  const float* X   = (const float*)d_in[0];
  const int*   ei  = (const int*)  d_in[1];
  const float* ew  = (const float*)d_in[2];
  const float* w1  = (const float*)d_in[3];
  const float* wc  = (const float*)d_in[4];
  const float* bc  = (const float*)d_in[5];
  const float* gam = (const float*)d_in[6];
  const float* bet = (const float*)d_in[7];
  const float* wih = (const float*)d_in[8];
  const float* whh = (const float*)d_in[9];
  const float* lb  = (const float*)d_in[10];
  const float* l1w = (const float*)d_in[11];
  const float* l1b = (const float*)d_in[12];
  const float* l2w = (const float*)d_in[13];
  const float* l2b = (const float*)d_in[14];
  float* outp = (float*)d_out;
  (void)n_in; (void)out_size; (void)ws_size;

  const int N = in_sizes[0] / (TT * FIN);
  const int E = in_sizes[1] / 2;
  const int* srcv = ei;
  const int* dstv = ei + E;

  char* base = (char*)d_ws;
  size_t off = 0;
  auto alloc = [&](size_t b) -> void* {
    void* p = base + off;
    off += (b + 255) & ~(size_t)255;
    return p;
  };

  u64*   pk     = (u64*)  alloc((size_t)N * 8);
  int*   epos   = (int*)  alloc((size_t)E * 4);
  int*   rowptr = (int*)  alloc(((size_t)N + 1) * 4);
  int*   partial= (int*)  alloc(1024);
  float* dinv   = (float*)alloc((size_t)N * 4);
  float* selfn  = (float*)alloc((size_t)N * 4);
  int2*  csr    = (int2*) alloc((size_t)E * 8);
  float* XA     = (float*)alloc((size_t)N * 12 * 4);
  u32*   Ga     = (u32*)  alloc((size_t)N * 64 * 4);   // bf16 pairs; doubles as H1
  u32*   Gb     = (u32*)  alloc((size_t)N * 64 * 4);   // doubles as H2
  u32*   Gfin   = (u32*)  alloc((size_t)3 * N * 64 * 4);
  u32*   Htb    = (u32*)  alloc((size_t)N * 64 * 4);
  float* c1buf  = (float*)alloc((size_t)N * HID * 4);
  float* c2buf  = (float*)alloc((size_t)N * HID * 4);
  float* statsb = (float*)alloc(16 * 256 * 4);
  int*   ticket = (int*)  alloc(256);
  float* aff    = (float*)alloc(256 * 4);
  float* aff3   = (float*)alloc((size_t)3 * 256 * 4);
  float* hw     = (float*)alloc(136 * 4);
  bf16x8* wcsw  = (bf16x8*)alloc((size_t)3 * 2048 * 16);
  bf16x8* wstk  = (bf16x8*)alloc((size_t)2 * 16384 * 16);

  int gN = (N + 255) / 256, gE = (E + 255) / 256;
  int nb = (N + 255) / 256;

  k_init<<<gN, 256, 0, stream>>>(pk, statsb, ticket, N);
  k_deg<<<gE, 256, 0, stream>>>(dstv, ew, pk, epos, E);
  k_scanA<<<nb, 256, 0, stream>>>(pk, rowptr, partial, dinv, selfn, N);
  k_scanB<<<1, 256, 0, stream>>>(partial, nb);
  k_scanC<<<nb, 256, 0, stream>>>(rowptr, partial, N);
  k_fillcsr<<<gE, 256, 0, stream>>>(srcv, dstv, ew, dinv, rowptr, epos, csr, E);
  k_aggX<<<1024, 256, 0, stream>>>(X, rowptr, csr, selfn, XA, N);
  k_swzall<<<152, 256, 0, stream>>>(wc, wih, whh, wcsw, wstk);
  k_headprep<<<1, 256, 0, stream>>>(l1w, l1b, l2w, l2b, hw);

  for (int t = 0; t < TT; ++t) {
    u32* Gt = Gfin + (size_t)t * N * 64;
    float* afft = aff3 + (size_t)t * 256;
    k_l0s<<<512, 256, 0, stream>>>(XA, w1, bc, Ga, statsb, ticket, gam, bet,
                                   aff, aff + HID, t, N);
    k_trans<<<(N + 63) / 64, 256, 0, stream>>>((const u16*)Ga, aff, aff + HID, wcsw,
                                               (u16*)Htb, N);
    k_aggs<<<1024, 256, 0, stream>>>(Htb, rowptr, csr, selfn, bc + HID, Gb,
                                     statsb, ticket, gam + HID, bet + HID,
                                     aff, aff + HID, N);
    k_trans<<<(N + 63) / 64, 256, 0, stream>>>((const u16*)Gb, aff, aff + HID, wcsw + 2048,
                                               (u16*)Htb, N);
    k_aggs<<<1024, 256, 0, stream>>>(Htb, rowptr, csr, selfn, bc + 2 * HID, Ga,
                                     statsb, ticket, gam + 2 * HID, bet + 2 * HID,
                                     aff, aff + HID, N);
    k_trans<<<(N + 63) / 64, 256, 0, stream>>>((const u16*)Ga, aff, aff + HID, wcsw + 4096,
                                               (u16*)Htb, N);
    k_aggs<<<1024, 256, 0, stream>>>(Htb, rowptr, csr, selfn, bc + 3 * HID, Gt,
                                     statsb, ticket, gam + 3 * HID, bet + 3 * HID,
                                     afft, afft + HID, N);
  }

  // LSTM: H1 aliases Ga, H2 aliases Gb (GCN ping-pong buffers are dead now)
  u16* H1 = (u16*)Ga;
  u16* H2 = (u16*)Gb;
  int gL = (N + 31) / 32;
  for (int t = 0; t < TT; ++t) {
    const u16* Gt = (const u16*)(Gfin + (size_t)t * N * 64);
    k_lstm2<<<gL, 256, 0, stream>>>(Gt, aff3 + (size_t)t * 256, H1, c1buf, H2, c2buf,
                                    wstk, wstk + 16384, lb, lb + 512,
                                    (t == 0) ? 1 : 0, N);
  }
  k_final2<<<512, 256, 0, stream>>>((const u32*)H2, X, hw, outp, N);
}